// Round 7
// baseline (264.369 us; speedup 1.0000x reference)
//
#include <hip/hip_runtime.h>
#include <math.h>

#define CB 16          // class_bit
#define ALPHA 0.1f
#define LOG2E 1.4426950408889634f
#define LN2F  0.6931471805599453f

typedef __bf16 bf16x8 __attribute__((ext_vector_type(8)));
typedef float  f32x16 __attribute__((ext_vector_type(16)));

__device__ inline float block_reduce_256(float v, float* red) {
    #pragma unroll
    for (int off = 32; off > 0; off >>= 1) v += __shfl_down(v, off, 64);
    int lane = threadIdx.x & 63;
    int wid  = threadIdx.x >> 6;
    if (lane == 0) red[wid] = v;
    __syncthreads();
    float s = 0.f;
    if (threadIdx.x == 0) {
        int nw = blockDim.x >> 6;
        for (int w = 0; w < nw; ++w) s += red[w];
    }
    return s;
}

// Fused prep:
//  blocks [0, nub):        u_[b,c,d] = sum_k u[b,k]*w_D[c,k,d]
//                          -> u_f32 [b][c][d], u_bf [c][b][d] (scaled by log2e),
//                             quantization partials
//  blocks [nub, nub+n_cls): v[c,d] = sum_k w_D[c,k,d]*yu[c,k],
//                           w[c,d] = sum_k w_D[c,k,d]*su[k]
//  block 0 thread 0 also resets the done-counter for the fused finalize.
__global__ __launch_bounds__(256) void prep_kernel(
        const float* __restrict__ u, const float* __restrict__ y,
        const float* __restrict__ w_D,
        float* __restrict__ u_f32, __bf16* __restrict__ u_bf,
        float* __restrict__ quant_partials,
        float* __restrict__ vvec, float* __restrict__ wvec,
        unsigned int* __restrict__ done_ctr,
        int n_bs, int bit, int n_cls, int nub) {
    __shared__ float red[4];
    __shared__ float yus[4][64];
    __shared__ float sus[4][64];
    if (blockIdx.x == 0 && threadIdx.x == 0) *done_ctr = 0u;
    if ((int)blockIdx.x < nub) {
        int idx = blockIdx.x * 256 + threadIdx.x;
        int total = n_bs * n_cls * CB;
        float q = 0.f;
        if (idx < total) {
            int d = idx & (CB - 1);
            int c = (idx / CB) % n_cls;
            int b = idx / (CB * n_cls);
            const float* __restrict__ ur = u + (size_t)b * bit;
            const float* __restrict__ w  = w_D + (size_t)c * bit * CB + d;
            float s = 0.f;
            for (int k = 0; k < bit; ++k) s = fmaf(ur[k], w[k * CB], s);
            u_f32[idx] = s;
            u_bf[((size_t)c * n_bs + b) * CB + d] = (__bf16)(s * LOG2E);
            float sgn = (s > 0.f) ? 1.f : ((s < 0.f) ? -1.f : 0.f);
            float dd = s - sgn;
            q = dd * dd;
        }
        float bs = block_reduce_256(q, red);
        if (threadIdx.x == 0) quant_partials[blockIdx.x] = bs;
    } else {
        const int c  = blockIdx.x - nub;
        const int kk = threadIdx.x & 63;       // k index (bit <= 64)
        const int sl = threadIdx.x >> 6;       // 4 b-slices
        float yv = 0.f, sv = 0.f;
        if (kk < bit) {
            const int bpp = n_bs >> 2;
            for (int b = sl * bpp; b < (sl + 1) * bpp; ++b) {
                float uv = u[(size_t)b * bit + kk];
                sv += uv;
                yv = fmaf(y[(size_t)b * n_cls + c], uv, yv);
            }
        }
        yus[sl][kk] = yv; sus[sl][kk] = sv;
        __syncthreads();
        if (sl == 0 && kk < bit) {
            yus[0][kk] = yus[0][kk] + yus[1][kk] + yus[2][kk] + yus[3][kk];
            sus[0][kk] = sus[0][kk] + sus[1][kk] + sus[2][kk] + sus[3][kk];
        }
        __syncthreads();
        if (threadIdx.x < CB) {
            const int d = threadIdx.x;
            const float* __restrict__ wdc = w_D + (size_t)c * bit * CB + d;
            float v = 0.f, w = 0.f;
            for (int k = 0; k < bit; ++k) {
                float wv = wdc[k * CB];
                v = fmaf(yus[0][k], wv, v);
                w = fmaf(sus[0][k], wv, w);
            }
            vvec[(size_t)c * CB + d] = v;
            wvec[(size_t)c * CB + d] = w;
        }
    }
}

// One block = 32-row t-tile x 4 classes (one class per wave, 4 MFMAs/wave).
// Patch rows via direct-store pflag (ind distinct -> no atomics).
// Per-lane combined scalar contribution -> single reduction tree.
// Last block to finish performs the global finalize (rocPRIM-style).
// NOTE: (256,4) is the spill-free config (VGPR ~48); (256,8) forced VGPR=32
// and spilled to scratch -> 11x slowdown (Round 6).
__global__ __launch_bounds__(256, 4) void loss_main_mfma(
        const float* __restrict__ y, const float* __restrict__ U,
        const float* __restrict__ Yb, const float* __restrict__ u_f32,
        const __bf16* __restrict__ u_bf,
        const float* __restrict__ vvec, const float* __restrict__ wvec,
        const int* __restrict__ ind, float* __restrict__ partials,
        const float* __restrict__ quant_partials,
        unsigned int* __restrict__ done_ctr, float* __restrict__ out,
        int nblk, int nub, int n_bs, int n_cls, int n_train,
        double pad_corr, double like_scale, double quant_scale) {
    __shared__ float red[4];
    __shared__ int pflag[32];
    __shared__ int islast;
    const int tid  = threadIdx.x;
    const int lane = tid & 63;
    const int wid  = tid >> 6;
    const int c    = blockIdx.x * 4 + wid;
    const int t0   = blockIdx.y * 32;
    const int r    = lane & 31;
    const int h    = lane >> 5;
    const int row  = t0 + r;

    if (tid < 32) pflag[tid] = -1;

    // unconditional parallel loads (common case); clamp pad rows
    const int rc = (row < n_train) ? row : (n_train - 1);
    const float* __restrict__ ar = U + ((size_t)rc * n_cls + c) * CB + h * 8;
    float4 a0 = *(const float4*)(ar);
    float4 a1 = *(const float4*)(ar + 4);
    float Yv = Yb[(size_t)rc * n_cls + c];

    __syncthreads();                       // pflag init visible
    if (tid < n_bs) {
        unsigned rl = (unsigned)(ind[tid] - t0);
        if (rl < 32u) pflag[rl] = tid;     // rows distinct -> no conflict
    }
    __syncthreads();                       // patch flags complete

    const int pf = pflag[r];
    if (pf >= 0) {
        const float* __restrict__ src =
            u_f32 + ((size_t)pf * n_cls + c) * CB + h * 8;
        a0 = *(const float4*)(src);
        a1 = *(const float4*)(src + 4);
        Yv = y[(size_t)pf * n_cls + c];
    }
    if (row >= n_train) {
        a0 = make_float4(0.f, 0.f, 0.f, 0.f); a1 = a0; Yv = 0.f;
    }

    // side dots: sum_b s*ip -> Yv*(U_row.v), sum_b ip -> U_row.w
    const float* __restrict__ vp = vvec + (size_t)c * CB + h * 8;
    const float* __restrict__ wp = wvec + (size_t)c * CB + h * 8;
    float sv = a0.x*vp[0] + a0.y*vp[1] + a0.z*vp[2] + a0.w*vp[3]
             + a1.x*vp[4] + a1.y*vp[5] + a1.z*vp[6] + a1.w*vp[7];
    float sw = a0.x*wp[0] + a0.y*wp[1] + a0.z*wp[2] + a0.w*wp[3]
             + a1.x*wp[4] + a1.y*wp[5] + a1.z*wp[6] + a1.w*wp[7];
    const float sideS = Yv * sv;
    const float sideW = sw;

    bf16x8 A;
    A[0] = (__bf16)a0.x; A[1] = (__bf16)a0.y;
    A[2] = (__bf16)a0.z; A[3] = (__bf16)a0.w;
    A[4] = (__bf16)a1.x; A[5] = (__bf16)a1.y;
    A[6] = (__bf16)a1.z; A[7] = (__bf16)a1.w;

    const __bf16* __restrict__ ub = u_bf + (size_t)c * n_bs * CB;
    bf16x8 B[4];
    #pragma unroll
    for (int bt = 0; bt < 4; ++bt)
        B[bt] = *(const bf16x8*)(ub + (size_t)(bt * 32 + r) * CB + h * 8);

    float accA = 0.f;   // sum |ip'|
    float pp   = 1.f;   // prod (1 + 2^-|ip'|); <= 2^64, f32-safe
    f32x16 zc = {};
    #pragma unroll
    for (int bt = 0; bt < 4; ++bt) {
        f32x16 D = __builtin_amdgcn_mfma_f32_32x32x16_bf16(A, B[bt], zc, 0, 0, 0);
        float a[16];
        #pragma unroll
        for (int j = 0; j < 16; ++j) {
            float ipa = fabsf(D[j]);
            a[j] = 1.0f + __builtin_amdgcn_exp2f(-ipa);  // neg-abs = src modifier
            accA += ipa;
        }
        #pragma unroll
        for (int s = 1; s < 16; s <<= 1)
            #pragma unroll
            for (int j = 0; j < 16; j += 2 * s) a[j] *= a[j + s];
        pp *= a[0];
    }
    float accL = __builtin_amdgcn_logf(pp);              // v_log_f32 = log2

    // combined per-lane contribution (finalize is linear in the 4 sums)
    float contrib = LN2F * accL + (0.5f * LN2F) * accA + 0.5f * sideW - sideS;

    #pragma unroll
    for (int off = 32; off > 0; off >>= 1)
        contrib += __shfl_down(contrib, off, 64);
    if (lane == 0) red[wid] = contrib;
    __syncthreads();
    if (tid == 0) {
        float s = red[0] + red[1] + red[2] + red[3];
        int bid = blockIdx.y * gridDim.x + blockIdx.x;
        partials[bid] = s;
        __threadfence();                                  // release
        unsigned int old = atomicAdd(done_ctr, 1u);
        islast = (old == (unsigned int)(nblk - 1)) ? 1 : 0;
    }
    __syncthreads();
    if (islast) {
        __threadfence();                                  // acquire
        double s = 0.0, q = 0.0;
        for (int i = tid; i < nblk; i += 256) s += (double)partials[i];
        for (int i = tid; i < nub;  i += 256) q += (double)quant_partials[i];
        #pragma unroll
        for (int off = 32; off > 0; off >>= 1) {
            s += __shfl_down(s, off, 64);
            q += __shfl_down(q, off, 64);
        }
        __shared__ double dred[4][2];
        if (lane == 0) { dred[wid][0] = s; dred[wid][1] = q; }
        __syncthreads();
        if (tid == 0) {
            double S = dred[0][0] + dred[1][0] + dred[2][0] + dred[3][0];
            double Q = dred[0][1] + dred[1][1] + dred[2][1] + dred[3][1];
            out[0] = (float)((S - pad_corr) * like_scale + Q * quant_scale);
        }
    }
}

extern "C" void kernel_launch(void* const* d_in, const int* in_sizes, int n_in,
                              void* d_out, int out_size, void* d_ws, size_t ws_size,
                              hipStream_t stream) {
    const float* u   = (const float*)d_in[0];
    const float* y   = (const float*)d_in[1];
    const int*   ind = (const int*)d_in[2];
    const float* U   = (const float*)d_in[3];
    const float* Yb  = (const float*)d_in[4];
    const float* w_D = (const float*)d_in[5];

    const int n_bs    = in_sizes[2];             // 128
    const int bit     = in_sizes[0] / n_bs;      // 48
    const int n_cls   = in_sizes[1] / n_bs;      // 100
    const int n_train = in_sizes[4] / n_cls;     // 10000

    const int totalU = n_bs * n_cls * CB;
    const int nub    = (totalU + 255) / 256;     // 800
    const int ntile  = (n_train + 31) / 32;      // 313
    const int gx     = (n_cls + 3) / 4;          // 25
    const int nblk   = ntile * gx;

    char* ws = (char*)d_ws;
    size_t off = 0;
    float* u_f32 = (float*)(ws + off);          off += (size_t)totalU * 4;
    __bf16* u_bf = (__bf16*)(ws + off);         off += (size_t)totalU * 2;
    off = (off + 15) & ~(size_t)15;
    float* vvec = (float*)(ws + off);           off += (size_t)n_cls * CB * 4;
    float* wvec = (float*)(ws + off);           off += (size_t)n_cls * CB * 4;
    float* quant_partials = (float*)(ws + off); off += (size_t)nub * 4;
    off = (off + 15) & ~(size_t)15;
    float* partials = (float*)(ws + off);       off += (size_t)nblk * 4;
    off = (off + 15) & ~(size_t)15;
    unsigned int* done_ctr = (unsigned int*)(ws + off); off += 16;

    prep_kernel<<<nub + n_cls, 256, 0, stream>>>(
        u, y, w_D, u_f32, u_bf, quant_partials, vvec, wvec, done_ctr,
        n_bs, bit, n_cls, nub);

    const double ln2 = 0.6931471805599453;
    const double n_pad = (double)((long long)(ntile * 32 - n_train) *
                                  (long long)n_bs * (long long)n_cls);
    const double pad_corr    = ln2 * n_pad;
    const double like_scale  = 1.0 / ((double)n_bs * n_train * n_cls);
    const double quant_scale = (double)ALPHA / (double)totalU;

    loss_main_mfma<<<dim3(gx, ntile), 256, 0, stream>>>(
        y, U, Yb, u_f32, u_bf, vvec, wvec, ind, partials, quant_partials,
        done_ctr, (float*)d_out, nblk, nub, n_bs, n_cls, n_train,
        pad_corr, like_scale, quant_scale);
}

// Round 8
// 51.215 us; speedup vs baseline: 5.1620x; 5.1620x over previous
//
#include <hip/hip_runtime.h>
#include <math.h>

#define CB 16          // class_bit
#define ALPHA 0.1f
#define LOG2E 1.4426950408889634f
#define LN2F  0.6931471805599453f

typedef __bf16 bf16x8 __attribute__((ext_vector_type(8)));
typedef float  f32x16 __attribute__((ext_vector_type(16)));

__device__ inline float block_reduce_256(float v, float* red) {
    #pragma unroll
    for (int off = 32; off > 0; off >>= 1) v += __shfl_down(v, off, 64);
    int lane = threadIdx.x & 63;
    int wid  = threadIdx.x >> 6;
    if (lane == 0) red[wid] = v;
    __syncthreads();
    float s = 0.f;
    if (threadIdx.x == 0) {
        int nw = blockDim.x >> 6;
        for (int w = 0; w < nw; ++w) s += red[w];
    }
    return s;
}

// Fused prep:
//  blocks [0, nub):        u_[b,c,d] = sum_k u[b,k]*w_D[c,k,d]
//                          -> u_f32 [b][c][d], u_bf [c][b][d] (scaled by log2e),
//                             quantization partials
//  blocks [nub, nub+n_cls): v[c,d] = sum_k w_D[c,k,d]*yu[c,k],
//                           w[c,d] = sum_k w_D[c,k,d]*su[k]
__global__ __launch_bounds__(256) void prep_kernel(
        const float* __restrict__ u, const float* __restrict__ y,
        const float* __restrict__ w_D,
        float* __restrict__ u_f32, __bf16* __restrict__ u_bf,
        float* __restrict__ quant_partials,
        float* __restrict__ vvec, float* __restrict__ wvec,
        int n_bs, int bit, int n_cls, int nub) {
    __shared__ float red[4];
    __shared__ float yus[4][64];
    __shared__ float sus[4][64];
    if ((int)blockIdx.x < nub) {
        int idx = blockIdx.x * 256 + threadIdx.x;
        int total = n_bs * n_cls * CB;
        float q = 0.f;
        if (idx < total) {
            int d = idx & (CB - 1);
            int c = (idx / CB) % n_cls;
            int b = idx / (CB * n_cls);
            const float* __restrict__ ur = u + (size_t)b * bit;
            const float* __restrict__ w  = w_D + (size_t)c * bit * CB + d;
            float s = 0.f;
            for (int k = 0; k < bit; ++k) s = fmaf(ur[k], w[k * CB], s);
            u_f32[idx] = s;
            u_bf[((size_t)c * n_bs + b) * CB + d] = (__bf16)(s * LOG2E);
            float sgn = (s > 0.f) ? 1.f : ((s < 0.f) ? -1.f : 0.f);
            float dd = s - sgn;
            q = dd * dd;
        }
        float bs = block_reduce_256(q, red);
        if (threadIdx.x == 0) quant_partials[blockIdx.x] = bs;
    } else {
        const int c  = blockIdx.x - nub;
        const int kk = threadIdx.x & 63;       // k index (bit <= 64)
        const int sl = threadIdx.x >> 6;       // 4 b-slices
        float yv = 0.f, sv = 0.f;
        if (kk < bit) {
            const int bpp = n_bs >> 2;
            for (int b = sl * bpp; b < (sl + 1) * bpp; ++b) {
                float uv = u[(size_t)b * bit + kk];
                sv += uv;
                yv = fmaf(y[(size_t)b * n_cls + c], uv, yv);
            }
        }
        yus[sl][kk] = yv; sus[sl][kk] = sv;
        __syncthreads();
        if (sl == 0 && kk < bit) {
            yus[0][kk] = yus[0][kk] + yus[1][kk] + yus[2][kk] + yus[3][kk];
            sus[0][kk] = sus[0][kk] + sus[1][kk] + sus[2][kk] + sus[3][kk];
        }
        __syncthreads();
        if (threadIdx.x < CB) {
            const int d = threadIdx.x;
            const float* __restrict__ wdc = w_D + (size_t)c * bit * CB + d;
            float v = 0.f, w = 0.f;
            for (int k = 0; k < bit; ++k) {
                float wv = wdc[k * CB];
                v = fmaf(yus[0][k], wv, v);
                w = fmaf(sus[0][k], wv, w);
            }
            vvec[(size_t)c * CB + d] = v;
            wvec[(size_t)c * CB + d] = w;
        }
    }
}

// One block = 32-row t-tile x 4 classes (one class per wave, 4 MFMAs/wave).
// Patch rows via direct-store pflag (ind distinct -> no atomics).
// Per-lane combined scalar contribution -> single reduction tree, 1 float/block.
// NO device fences / cross-block sync here (Round 6/7 lesson: __threadfence
// per block forces an L2 writeback on CDNA -> 12x slowdown). Finalize is a
// separate kernel; kernel boundary provides ordering.
__global__ __launch_bounds__(256, 4) void loss_main_mfma(
        const float* __restrict__ y, const float* __restrict__ U,
        const float* __restrict__ Yb, const float* __restrict__ u_f32,
        const __bf16* __restrict__ u_bf,
        const float* __restrict__ vvec, const float* __restrict__ wvec,
        const int* __restrict__ ind, float* __restrict__ partials,
        int n_bs, int n_cls, int n_train) {
    __shared__ float red[4];
    __shared__ int pflag[32];
    const int tid  = threadIdx.x;
    const int lane = tid & 63;
    const int wid  = tid >> 6;
    const int c    = blockIdx.x * 4 + wid;
    const int t0   = blockIdx.y * 32;
    const int r    = lane & 31;
    const int h    = lane >> 5;
    const int row  = t0 + r;

    if (tid < 32) pflag[tid] = -1;

    // unconditional parallel loads (common case); clamp pad rows
    const int rc = (row < n_train) ? row : (n_train - 1);
    const float* __restrict__ ar = U + ((size_t)rc * n_cls + c) * CB + h * 8;
    float4 a0 = *(const float4*)(ar);
    float4 a1 = *(const float4*)(ar + 4);
    float Yv = Yb[(size_t)rc * n_cls + c];

    __syncthreads();                       // pflag init visible
    if (tid < n_bs) {
        unsigned rl = (unsigned)(ind[tid] - t0);
        if (rl < 32u) pflag[rl] = tid;     // rows distinct -> no conflict
    }
    __syncthreads();                       // patch flags complete

    const int pf = pflag[r];
    if (pf >= 0) {
        const float* __restrict__ src =
            u_f32 + ((size_t)pf * n_cls + c) * CB + h * 8;
        a0 = *(const float4*)(src);
        a1 = *(const float4*)(src + 4);
        Yv = y[(size_t)pf * n_cls + c];
    }
    if (row >= n_train) {
        a0 = make_float4(0.f, 0.f, 0.f, 0.f); a1 = a0; Yv = 0.f;
    }

    // side dots: sum_b s*ip -> Yv*(U_row.v), sum_b ip -> U_row.w
    const float* __restrict__ vp = vvec + (size_t)c * CB + h * 8;
    const float* __restrict__ wp = wvec + (size_t)c * CB + h * 8;
    float sv = a0.x*vp[0] + a0.y*vp[1] + a0.z*vp[2] + a0.w*vp[3]
             + a1.x*vp[4] + a1.y*vp[5] + a1.z*vp[6] + a1.w*vp[7];
    float sw = a0.x*wp[0] + a0.y*wp[1] + a0.z*wp[2] + a0.w*wp[3]
             + a1.x*wp[4] + a1.y*wp[5] + a1.z*wp[6] + a1.w*wp[7];
    const float sideS = Yv * sv;
    const float sideW = sw;

    bf16x8 A;
    A[0] = (__bf16)a0.x; A[1] = (__bf16)a0.y;
    A[2] = (__bf16)a0.z; A[3] = (__bf16)a0.w;
    A[4] = (__bf16)a1.x; A[5] = (__bf16)a1.y;
    A[6] = (__bf16)a1.z; A[7] = (__bf16)a1.w;

    const __bf16* __restrict__ ub = u_bf + (size_t)c * n_bs * CB;
    bf16x8 B[4];
    #pragma unroll
    for (int bt = 0; bt < 4; ++bt)
        B[bt] = *(const bf16x8*)(ub + (size_t)(bt * 32 + r) * CB + h * 8);

    float accA = 0.f;   // sum |ip'|
    float pp   = 1.f;   // prod (1 + 2^-|ip'|); <= 2^64, f32-safe
    f32x16 zc = {};
    #pragma unroll
    for (int bt = 0; bt < 4; ++bt) {
        f32x16 D = __builtin_amdgcn_mfma_f32_32x32x16_bf16(A, B[bt], zc, 0, 0, 0);
        float a[16];
        #pragma unroll
        for (int j = 0; j < 16; ++j) {
            float ipa = fabsf(D[j]);
            a[j] = 1.0f + __builtin_amdgcn_exp2f(-ipa);  // neg-abs = src modifier
            accA += ipa;
        }
        #pragma unroll
        for (int s = 1; s < 16; s <<= 1)
            #pragma unroll
            for (int j = 0; j < 16; j += 2 * s) a[j] *= a[j + s];
        pp *= a[0];
    }
    float accL = __builtin_amdgcn_logf(pp);              // v_log_f32 = log2

    // combined per-lane contribution (finalize is linear in the 4 sums);
    // pad rows contribute exactly LN2F each (pp *= 2), corrected on host side.
    float contrib = LN2F * accL + (0.5f * LN2F) * accA + 0.5f * sideW - sideS;

    #pragma unroll
    for (int off = 32; off > 0; off >>= 1)
        contrib += __shfl_down(contrib, off, 64);
    if (lane == 0) red[wid] = contrib;
    __syncthreads();
    if (tid == 0) {
        int bid = blockIdx.y * gridDim.x + blockIdx.x;
        partials[bid] = red[0] + red[1] + red[2] + red[3];
    }
}

__global__ __launch_bounds__(256) void finalize_kernel(
        const float* __restrict__ partials, int nblk,
        const float* __restrict__ quant_partials, int n_quant,
        float* __restrict__ out, double pad_corr,
        double like_scale, double quant_scale) {
    double s = 0.0, q = 0.0;
    for (int i = threadIdx.x; i < nblk; i += 256) s += (double)partials[i];
    for (int i = threadIdx.x; i < n_quant; i += 256) q += (double)quant_partials[i];
    #pragma unroll
    for (int off = 32; off > 0; off >>= 1) {
        s += __shfl_down(s, off, 64);
        q += __shfl_down(q, off, 64);
    }
    __shared__ double dred[4][2];
    int lane = threadIdx.x & 63, wid = threadIdx.x >> 6;
    if (lane == 0) { dred[wid][0] = s; dred[wid][1] = q; }
    __syncthreads();
    if (threadIdx.x == 0) {
        double S = dred[0][0] + dred[1][0] + dred[2][0] + dred[3][0];
        double Q = dred[0][1] + dred[1][1] + dred[2][1] + dred[3][1];
        out[0] = (float)((S - pad_corr) * like_scale + Q * quant_scale);
    }
}

extern "C" void kernel_launch(void* const* d_in, const int* in_sizes, int n_in,
                              void* d_out, int out_size, void* d_ws, size_t ws_size,
                              hipStream_t stream) {
    const float* u   = (const float*)d_in[0];
    const float* y   = (const float*)d_in[1];
    const int*   ind = (const int*)d_in[2];
    const float* U   = (const float*)d_in[3];
    const float* Yb  = (const float*)d_in[4];
    const float* w_D = (const float*)d_in[5];

    const int n_bs    = in_sizes[2];             // 128
    const int bit     = in_sizes[0] / n_bs;      // 48
    const int n_cls   = in_sizes[1] / n_bs;      // 100
    const int n_train = in_sizes[4] / n_cls;     // 10000

    const int totalU = n_bs * n_cls * CB;
    const int nub    = (totalU + 255) / 256;     // 800
    const int ntile  = (n_train + 31) / 32;      // 313
    const int gx     = (n_cls + 3) / 4;          // 25
    const int nblk   = ntile * gx;

    char* ws = (char*)d_ws;
    size_t off = 0;
    float* u_f32 = (float*)(ws + off);          off += (size_t)totalU * 4;
    __bf16* u_bf = (__bf16*)(ws + off);         off += (size_t)totalU * 2;
    off = (off + 15) & ~(size_t)15;
    float* vvec = (float*)(ws + off);           off += (size_t)n_cls * CB * 4;
    float* wvec = (float*)(ws + off);           off += (size_t)n_cls * CB * 4;
    float* quant_partials = (float*)(ws + off); off += (size_t)nub * 4;
    off = (off + 15) & ~(size_t)15;
    float* partials = (float*)(ws + off);       off += (size_t)nblk * 4;

    prep_kernel<<<nub + n_cls, 256, 0, stream>>>(
        u, y, w_D, u_f32, u_bf, quant_partials, vvec, wvec,
        n_bs, bit, n_cls, nub);

    loss_main_mfma<<<dim3(gx, ntile), 256, 0, stream>>>(
        y, U, Yb, u_f32, u_bf, vvec, wvec, ind, partials,
        n_bs, n_cls, n_train);

    const double ln2 = 0.6931471805599453;
    const double n_pad = (double)((long long)(ntile * 32 - n_train) *
                                  (long long)n_bs * (long long)n_cls);
    const double pad_corr    = ln2 * n_pad;
    const double like_scale  = 1.0 / ((double)n_bs * n_train * n_cls);
    const double quant_scale = (double)ALPHA / (double)totalU;

    finalize_kernel<<<1, 256, 0, stream>>>(partials, nblk, quant_partials, nub,
                                           (float*)d_out, pad_corr,
                                           like_scale, quant_scale);
}